// Round 4
// baseline (901.869 us; speedup 1.0000x reference)
//
#include <hip/hip_runtime.h>

#define NN 100000
#define D 64
#define BN_EPS 1e-5f

// ================= CSR path =================

__global__ void k_zero_cnt(int* cnt, int n) {
    int i = blockIdx.x * blockDim.x + threadIdx.x;
    if (i < n) cnt[i] = 0;
}

__global__ void k_count(const int* __restrict__ src, const int* __restrict__ dst,
                        int* cnt, int E) {
    int e = blockIdx.x * blockDim.x + threadIdx.x;
    if (e < E) {
        int s = src[e], d = dst[e];
        if (s != d) atomicAdd(&cnt[d], 1);
    }
}

__global__ void k_dinv_i(const int* __restrict__ cnt, float* dinv, int n) {
    int i = blockIdx.x * blockDim.x + threadIdx.x;
    if (i < n) dinv[i] = rsqrtf((float)cnt[i] + 1.0f);  // +1 self loop
}

// exclusive scan of cnt -> row_ptr, 3 phases
__global__ __launch_bounds__(1024) void k_scanA(const int* __restrict__ cnt,
                                                int* __restrict__ row_ptr,
                                                int* __restrict__ bsum, int n) {
    __shared__ int sm[1024];
    int tid = threadIdx.x;
    int i = blockIdx.x * 1024 + tid;
    int v = (i < n) ? cnt[i] : 0;
    int xv = v;
    sm[tid] = xv;
    __syncthreads();
    for (int off = 1; off < 1024; off <<= 1) {
        int t = (tid >= off) ? sm[tid - off] : 0;
        __syncthreads();
        xv += t;
        sm[tid] = xv;
        __syncthreads();
    }
    if (i < n) row_ptr[i] = xv - v;          // local exclusive
    if (tid == 1023) bsum[blockIdx.x] = xv;  // block total
}

__global__ void k_scanB(int* bsum, int nb) {
    __shared__ int sm[128];
    int tid = threadIdx.x;
    int v = (tid < nb) ? bsum[tid] : 0;
    int xv = v;
    sm[tid] = xv;
    __syncthreads();
    for (int off = 1; off < 128; off <<= 1) {
        int t = (tid >= off) ? sm[tid - off] : 0;
        __syncthreads();
        xv += t;
        sm[tid] = xv;
        __syncthreads();
    }
    if (tid < nb) bsum[tid] = xv - v;  // exclusive block offsets
}

__global__ void k_scanC(int* __restrict__ row_ptr, int* __restrict__ cursor,
                        const int* __restrict__ bsum, int n) {
    int i = blockIdx.x * blockDim.x + threadIdx.x;
    if (i < n) {
        int r = row_ptr[i] + bsum[i >> 10];
        row_ptr[i] = r;
        cursor[i] = r;
    }
}

__global__ void k_place(const int* __restrict__ src, const int* __restrict__ dst,
                        int* cursor, int* __restrict__ srcid, int E) {
    int e = blockIdx.x * blockDim.x + threadIdx.x;
    if (e < E) {
        int s = src[e], d = dst[e];
        if (s != d) {
            int pos = atomicAdd(&cursor[d], 1);
            srcid[pos] = s;
        }
    }
}

// one wave per node, lane = channel, 4-edge ILP
__global__ __launch_bounds__(256) void k_gather(const int* __restrict__ row_ptr,
                                                const int* __restrict__ cnt,
                                                const int* __restrict__ srcid,
                                                const float* __restrict__ x,
                                                const float* __restrict__ dinv,
                                                float* __restrict__ out, int n) {
    int wave = threadIdx.x >> 6, lane = threadIdx.x & 63;
    int d = blockIdx.x * 4 + wave;
    if (d >= n) return;
    int base = row_ptr[d];
    int c = cnt[d];
    float did = dinv[d];
    float acc = x[(size_t)d * D + lane] * did * did;  // self loop
    int j = 0;
    for (; j + 4 <= c; j += 4) {
        int s0 = srcid[base + j], s1 = srcid[base + j + 1];
        int s2 = srcid[base + j + 2], s3 = srcid[base + j + 3];
        float w0 = dinv[s0] * did, w1 = dinv[s1] * did;
        float w2 = dinv[s2] * did, w3 = dinv[s3] * did;
        float v0 = x[(size_t)s0 * D + lane];
        float v1 = x[(size_t)s1 * D + lane];
        float v2 = x[(size_t)s2 * D + lane];
        float v3 = x[(size_t)s3 * D + lane];
        acc += v0 * w0 + v1 * w1 + v2 * w2 + v3 * w3;
    }
    for (; j < c; ++j) {
        int s = srcid[base + j];
        acc += x[(size_t)s * D + lane] * (dinv[s] * did);
    }
    out[(size_t)d * D + lane] = acc;
}

// ================= fallback (small ws): atomic scatter =================

__global__ void k_deg_init(float* deg, int n) {
    int i = blockIdx.x * blockDim.x + threadIdx.x;
    if (i < n) deg[i] = 1.0f;
}

__global__ void k_deg_edges(const int* __restrict__ src, const int* __restrict__ dst,
                            float* deg, int E) {
    int e = blockIdx.x * blockDim.x + threadIdx.x;
    if (e < E) {
        int s = src[e], d = dst[e];
        if (s != d) atomicAdd(&deg[d], 1.0f);
    }
}

__global__ void k_dinv_f(float* deg, int n) {
    int i = blockIdx.x * blockDim.x + threadIdx.x;
    if (i < n) deg[i] = rsqrtf(deg[i]);
}

__global__ void k_agg_init(const float* __restrict__ x, const float* __restrict__ dinv,
                           float* __restrict__ out, int n) {
    int i = blockIdx.x * blockDim.x + threadIdx.x;
    if (i < n * D) {
        int row = i >> 6;
        float di = dinv[row];
        out[i] = x[i] * di * di;
    }
}

__global__ __launch_bounds__(256) void k_scatter(const int* __restrict__ src,
                                                 const int* __restrict__ dst,
                                                 const float* __restrict__ x,
                                                 const float* __restrict__ dinv,
                                                 float* out, int E) {
    int gw = (int)((blockIdx.x * blockDim.x + threadIdx.x) >> 6);
    int lane = threadIdx.x & 63;
    if (gw >= E) return;
    int s = src[gw], d = dst[gw];
    if (s == d) return;
    float w = dinv[s] * dinv[d];
    atomicAdd(&out[(size_t)d * D + lane], x[(size_t)s * D + lane] * w);
}

// ================= GEMM + BN =================

__global__ void k_zero_stats(float* sums) {
    int i = threadIdx.x;
    if (i < 128) sums[i] = 0.0f;
}

__global__ __launch_bounds__(256) void k_gemm_stats(float* __restrict__ out,
                                                    const float* __restrict__ W,
                                                    float* sums, int n) {
    __shared__ float Ws[64 * 64];
    int tid = threadIdx.x;
    for (int i = tid; i < 64 * 64; i += 256) Ws[i] = W[i];
    __syncthreads();
    int wave = tid >> 6, lane = tid & 63;
    int row = blockIdx.x * 4 + wave;
    bool valid = row < n;
    float xv = valid ? out[(size_t)row * D + lane] : 0.0f;
    float acc = 0.0f;
#pragma unroll
    for (int k = 0; k < 64; ++k) {
        acc += __shfl(xv, k) * Ws[k * 64 + lane];
    }
    if (valid) out[(size_t)row * D + lane] = acc;
    __shared__ float ls[4][64], lq[4][64];
    float a = valid ? acc : 0.0f;
    ls[wave][lane] = a;
    lq[wave][lane] = a * a;
    __syncthreads();
    if (wave == 0) {
        float ts = ls[0][lane] + ls[1][lane] + ls[2][lane] + ls[3][lane];
        float tq = lq[0][lane] + lq[1][lane] + lq[2][lane] + lq[3][lane];
        atomicAdd(&sums[lane], ts);
        atomicAdd(&sums[64 + lane], tq);
    }
}

// GCN bias b cancels exactly in BatchNorm: omitted.
__global__ void k_bn_apply(float* out, const float* __restrict__ sums,
                           const float* __restrict__ bnw, const float* __restrict__ bnb,
                           int n) {
    int i = blockIdx.x * blockDim.x + threadIdx.x;
    if (i >= n * D) return;
    int c = i & 63;
    const float invn = 1.0f / (float)NN;
    float mean = sums[c] * invn;
    float var = sums[64 + c] * invn - mean * mean;
    if (var < 0.0f) var = 0.0f;
    float scale = bnw[c] * rsqrtf(var + BN_EPS);
    float v = (out[i] - mean) * scale + bnb[c];
    out[i] = v > 0.0f ? v : 0.0f;
}

extern "C" void kernel_launch(void* const* d_in, const int* in_sizes, int n_in,
                              void* d_out, int out_size, void* d_ws, size_t ws_size,
                              hipStream_t stream) {
    const float* x = (const float*)d_in[0];
    const int* ei = (const int*)d_in[1];
    const float* W = (const float*)d_in[3];
    const float* bnw = (const float*)d_in[5];
    const float* bnb = (const float*)d_in[6];
    float* out = (float*)d_out;

    const int n = in_sizes[0] / D;   // 100000
    const int E = in_sizes[1] / 2;   // 1600000
    const int* src = ei;
    const int* dst = ei + E;

    const size_t need = ((size_t)4 * n + (size_t)E + 256) * 4;  // ~8.0 MB

    if (ws_size >= need) {
        // ---- CSR path ----
        int* cnt = (int*)d_ws;
        int* row_ptr = cnt + n;
        int* cursor = row_ptr + n;
        float* dinv = (float*)(cursor + n);
        int* srcid = (int*)(dinv + n);
        int* bsum = srcid + E;          // 128 ints
        float* sums = (float*)(bsum + 128);

        const int nb = (n + 1023) / 1024;  // 98

        k_zero_cnt<<<(n + 255) / 256, 256, 0, stream>>>(cnt, n);
        k_count<<<(E + 255) / 256, 256, 0, stream>>>(src, dst, cnt, E);
        k_dinv_i<<<(n + 255) / 256, 256, 0, stream>>>(cnt, dinv, n);
        k_scanA<<<nb, 1024, 0, stream>>>(cnt, row_ptr, bsum, n);
        k_scanB<<<1, 128, 0, stream>>>(bsum, nb);
        k_scanC<<<(n + 255) / 256, 256, 0, stream>>>(row_ptr, cursor, bsum, n);
        k_place<<<(E + 255) / 256, 256, 0, stream>>>(src, dst, cursor, srcid, E);
        k_gather<<<(n + 3) / 4, 256, 0, stream>>>(row_ptr, cnt, srcid, x, dinv, out, n);

        k_zero_stats<<<1, 128, 0, stream>>>(sums);
        k_gemm_stats<<<(n + 3) / 4, 256, 0, stream>>>(out, W, sums, n);
        k_bn_apply<<<(n * D + 255) / 256, 256, 0, stream>>>(out, sums, bnw, bnb, n);
    } else {
        // ---- fallback: atomic scatter (proven R1 path) ----
        float* dinv = (float*)d_ws;
        float* sums = dinv + n;

        k_deg_init<<<(n + 255) / 256, 256, 0, stream>>>(dinv, n);
        k_deg_edges<<<(E + 255) / 256, 256, 0, stream>>>(src, dst, dinv, E);
        k_dinv_f<<<(n + 255) / 256, 256, 0, stream>>>(dinv, n);
        k_agg_init<<<(n * D + 255) / 256, 256, 0, stream>>>(x, dinv, out, n);
        k_scatter<<<(E + 3) / 4, 256, 0, stream>>>(src, dst, x, dinv, out, E);
        k_zero_stats<<<1, 128, 0, stream>>>(sums);
        k_gemm_stats<<<(n + 3) / 4, 256, 0, stream>>>(out, W, sums, n);
        k_bn_apply<<<(n * D + 255) / 256, 256, 0, stream>>>(out, sums, bnw, bnb, n);
    }
}

// Round 5
// 371.894 us; speedup vs baseline: 2.4251x; 2.4251x over previous
//
#include <hip/hip_runtime.h>

#define NN 100000
#define D 64
#define BN_EPS 1e-5f

// ================= CSR build =================

__global__ void k_zero_cnt(int* cnt, int n) {
    int i = blockIdx.x * blockDim.x + threadIdx.x;
    if (i < n) cnt[i] = 0;
}

__global__ void k_count(const int* __restrict__ src, const int* __restrict__ dst,
                        int* cnt, int E) {
    int e = blockIdx.x * blockDim.x + threadIdx.x;
    if (e < E) {
        int s = src[e], d = dst[e];
        if (s != d) atomicAdd(&cnt[d], 1);
    }
}

__global__ void k_dinv_i(const int* __restrict__ cnt, float* dinv, int n) {
    int i = blockIdx.x * blockDim.x + threadIdx.x;
    if (i < n) dinv[i] = rsqrtf((float)cnt[i] + 1.0f);  // +1 self loop
}

// exclusive scan of cnt -> row_ptr, 3 phases
__global__ __launch_bounds__(1024) void k_scanA(const int* __restrict__ cnt,
                                                int* __restrict__ row_ptr,
                                                int* __restrict__ bsum, int n) {
    __shared__ int sm[1024];
    int tid = threadIdx.x;
    int i = blockIdx.x * 1024 + tid;
    int v = (i < n) ? cnt[i] : 0;
    int xv = v;
    sm[tid] = xv;
    __syncthreads();
    for (int off = 1; off < 1024; off <<= 1) {
        int t = (tid >= off) ? sm[tid - off] : 0;
        __syncthreads();
        xv += t;
        sm[tid] = xv;
        __syncthreads();
    }
    if (i < n) row_ptr[i] = xv - v;          // local exclusive
    if (tid == 1023) bsum[blockIdx.x] = xv;  // block total
}

__global__ void k_scanB(int* bsum, int nb) {
    __shared__ int sm[128];
    int tid = threadIdx.x;
    int v = (tid < nb) ? bsum[tid] : 0;
    int xv = v;
    sm[tid] = xv;
    __syncthreads();
    for (int off = 1; off < 128; off <<= 1) {
        int t = (tid >= off) ? sm[tid - off] : 0;
        __syncthreads();
        xv += t;
        sm[tid] = xv;
        __syncthreads();
    }
    if (tid < nb) bsum[tid] = xv - v;  // exclusive block offsets
}

__global__ void k_scanC(int* __restrict__ row_ptr, int* __restrict__ cursor,
                        const int* __restrict__ bsum, int n) {
    int i = blockIdx.x * blockDim.x + threadIdx.x;
    if (i < n) {
        int r = row_ptr[i] + bsum[i >> 10];
        row_ptr[i] = r;
        cursor[i] = r;
    }
}

__global__ void k_place(const int* __restrict__ src, const int* __restrict__ dst,
                        int* cursor, int* __restrict__ srcid, int E) {
    int e = blockIdx.x * blockDim.x + threadIdx.x;
    if (e < E) {
        int s = src[e], d = dst[e];
        if (s != d) {
            int pos = atomicAdd(&cursor[d], 1);
            srcid[pos] = s;
        }
    }
}

// one wave per node, lane = channel, 4-edge ILP
__global__ __launch_bounds__(256) void k_gather(const int* __restrict__ row_ptr,
                                                const int* __restrict__ cnt,
                                                const int* __restrict__ srcid,
                                                const float* __restrict__ x,
                                                const float* __restrict__ dinv,
                                                float* __restrict__ out, int n) {
    int wave = threadIdx.x >> 6, lane = threadIdx.x & 63;
    int d = blockIdx.x * 4 + wave;
    if (d >= n) return;
    int base = row_ptr[d];
    int c = cnt[d];
    float did = dinv[d];
    float acc = x[(size_t)d * D + lane] * did * did;  // self loop
    int j = 0;
    for (; j + 4 <= c; j += 4) {
        int s0 = srcid[base + j], s1 = srcid[base + j + 1];
        int s2 = srcid[base + j + 2], s3 = srcid[base + j + 3];
        float w0 = dinv[s0] * did, w1 = dinv[s1] * did;
        float w2 = dinv[s2] * did, w3 = dinv[s3] * did;
        float v0 = x[(size_t)s0 * D + lane];
        float v1 = x[(size_t)s1 * D + lane];
        float v2 = x[(size_t)s2 * D + lane];
        float v3 = x[(size_t)s3 * D + lane];
        acc += v0 * w0 + v1 * w1 + v2 * w2 + v3 * w3;
    }
    for (; j < c; ++j) {
        int s = srcid[base + j];
        acc += x[(size_t)s * D + lane] * (dinv[s] * did);
    }
    out[(size_t)d * D + lane] = acc;
}

// ================= fallback (small ws): atomic scatter =================

__global__ void k_deg_init(float* deg, int n) {
    int i = blockIdx.x * blockDim.x + threadIdx.x;
    if (i < n) deg[i] = 1.0f;
}

__global__ void k_deg_edges(const int* __restrict__ src, const int* __restrict__ dst,
                            float* deg, int E) {
    int e = blockIdx.x * blockDim.x + threadIdx.x;
    if (e < E) {
        int s = src[e], d = dst[e];
        if (s != d) atomicAdd(&deg[d], 1.0f);
    }
}

__global__ void k_dinv_f(float* deg, int n) {
    int i = blockIdx.x * blockDim.x + threadIdx.x;
    if (i < n) deg[i] = rsqrtf(deg[i]);
}

__global__ void k_agg_init(const float* __restrict__ x, const float* __restrict__ dinv,
                           float* __restrict__ out, int n) {
    int i = blockIdx.x * blockDim.x + threadIdx.x;
    if (i < n * D) {
        int row = i >> 6;
        float di = dinv[row];
        out[i] = x[i] * di * di;
    }
}

__global__ __launch_bounds__(256) void k_scatter(const int* __restrict__ src,
                                                 const int* __restrict__ dst,
                                                 const float* __restrict__ x,
                                                 const float* __restrict__ dinv,
                                                 float* out, int E) {
    int gw = (int)((blockIdx.x * blockDim.x + threadIdx.x) >> 6);
    int lane = threadIdx.x & 63;
    if (gw >= E) return;
    int s = src[gw], d = dst[gw];
    if (s == d) return;
    float w = dinv[s] * dinv[d];
    atomicAdd(&out[(size_t)d * D + lane], x[(size_t)s * D + lane] * w);
}

// ================= GEMM + BN =================

__global__ void k_zero_stats(float* sums) {
    int i = threadIdx.x;
    if (i < 128) sums[i] = 0.0f;
}

// grid-stride (launch with <=1024 blocks): partial sums in registers,
// one 128-atomic flush per block -> no same-line atomic pileup.
__global__ __launch_bounds__(256) void k_gemm_stats(float* __restrict__ out,
                                                    const float* __restrict__ W,
                                                    float* sums, int n) {
    __shared__ float Ws[64 * 64];
    int tid = threadIdx.x;
    for (int i = tid; i < 64 * 64; i += 256) Ws[i] = W[i];
    __syncthreads();
    int wave = tid >> 6, lane = tid & 63;
    float s = 0.0f, sq = 0.0f;
    for (int row = blockIdx.x * 4 + wave; row < n; row += gridDim.x * 4) {
        float xv = out[(size_t)row * D + lane];
        float acc = 0.0f;
#pragma unroll
        for (int k = 0; k < 64; ++k) {
            acc += __shfl(xv, k) * Ws[k * 64 + lane];
        }
        out[(size_t)row * D + lane] = acc;
        s += acc;
        sq += acc * acc;
    }
    __shared__ float ls[4][64], lq[4][64];
    ls[wave][lane] = s;
    lq[wave][lane] = sq;
    __syncthreads();
    if (wave == 0) {
        float ts = ls[0][lane] + ls[1][lane] + ls[2][lane] + ls[3][lane];
        float tq = lq[0][lane] + lq[1][lane] + lq[2][lane] + lq[3][lane];
        atomicAdd(&sums[lane], ts);
        atomicAdd(&sums[64 + lane], tq);
    }
}

// GCN bias b cancels exactly in BatchNorm: omitted.
__global__ void k_bn_apply(float* out, const float* __restrict__ sums,
                           const float* __restrict__ bnw, const float* __restrict__ bnb,
                           int n) {
    int i = blockIdx.x * blockDim.x + threadIdx.x;
    if (i >= n * D) return;
    int c = i & 63;
    const float invn = 1.0f / (float)NN;
    float mean = sums[c] * invn;
    float var = sums[64 + c] * invn - mean * mean;
    if (var < 0.0f) var = 0.0f;
    float scale = bnw[c] * rsqrtf(var + BN_EPS);
    float v = (out[i] - mean) * scale + bnb[c];
    out[i] = v > 0.0f ? v : 0.0f;
}

extern "C" void kernel_launch(void* const* d_in, const int* in_sizes, int n_in,
                              void* d_out, int out_size, void* d_ws, size_t ws_size,
                              hipStream_t stream) {
    const float* x = (const float*)d_in[0];
    const int* ei = (const int*)d_in[1];
    const float* W = (const float*)d_in[3];
    const float* bnw = (const float*)d_in[5];
    const float* bnb = (const float*)d_in[6];
    float* out = (float*)d_out;

    const int n = in_sizes[0] / D;   // 100000
    const int E = in_sizes[1] / 2;   // 1600000
    const int* src = ei;
    const int* dst = ei + E;

    const size_t need = ((size_t)4 * n + (size_t)E + 256) * 4;  // ~8.0 MB

    if (ws_size >= need) {
        // ---- CSR path ----
        int* cnt = (int*)d_ws;
        int* row_ptr = cnt + n;
        int* cursor = row_ptr + n;
        float* dinv = (float*)(cursor + n);
        int* srcid = (int*)(dinv + n);
        int* bsum = srcid + E;          // 128 ints
        float* sums = (float*)(bsum + 128);

        const int nb = (n + 1023) / 1024;  // 98

        k_zero_cnt<<<(n + 255) / 256, 256, 0, stream>>>(cnt, n);
        k_count<<<(E + 255) / 256, 256, 0, stream>>>(src, dst, cnt, E);
        k_dinv_i<<<(n + 255) / 256, 256, 0, stream>>>(cnt, dinv, n);
        k_scanA<<<nb, 1024, 0, stream>>>(cnt, row_ptr, bsum, n);
        k_scanB<<<1, 128, 0, stream>>>(bsum, nb);
        k_scanC<<<(n + 255) / 256, 256, 0, stream>>>(row_ptr, cursor, bsum, n);
        k_place<<<(E + 255) / 256, 256, 0, stream>>>(src, dst, cursor, srcid, E);
        k_gather<<<(n + 3) / 4, 256, 0, stream>>>(row_ptr, cnt, srcid, x, dinv, out, n);

        k_zero_stats<<<1, 128, 0, stream>>>(sums);
        k_gemm_stats<<<1024, 256, 0, stream>>>(out, W, sums, n);
        k_bn_apply<<<(n * D + 255) / 256, 256, 0, stream>>>(out, sums, bnw, bnb, n);
    } else {
        // ---- fallback: atomic scatter (proven R1 path) ----
        float* dinv = (float*)d_ws;
        float* sums = dinv + n;

        k_deg_init<<<(n + 255) / 256, 256, 0, stream>>>(dinv, n);
        k_deg_edges<<<(E + 255) / 256, 256, 0, stream>>>(src, dst, dinv, E);
        k_dinv_f<<<(n + 255) / 256, 256, 0, stream>>>(dinv, n);
        k_agg_init<<<(n * D + 255) / 256, 256, 0, stream>>>(x, dinv, out, n);
        k_scatter<<<(E + 3) / 4, 256, 0, stream>>>(src, dst, x, dinv, out, E);
        k_zero_stats<<<1, 128, 0, stream>>>(sums);
        k_gemm_stats<<<1024, 256, 0, stream>>>(out, W, sums, n);
        k_bn_apply<<<(n * D + 255) / 256, 256, 0, stream>>>(out, sums, bnw, bnb, n);
    }
}